// Round 1
// baseline (170.520 us; speedup 1.0000x reference)
//
#include <hip/hip_runtime.h>

// CARAFE++ downsample: B=8, C=128, H=W=160, stride 2 -> HD=WD=80
// stage1: 1x1 conv 128->16          (compress)
// stage2: 3x3 s2 conv 16->25 + softmax (encoder)
// stage3: 5x5 stride-2 content-aware reassembly

#define B   8
#define C   128
#define H   160
#define W   160
#define CM  16
#define KC  25
#define HD  80
#define WD  80

__global__ __launch_bounds__(256) void compress_k(const float* __restrict__ x,
                                                  const float* __restrict__ wc,
                                                  float* __restrict__ comp) {
    int tid = blockIdx.x * 256 + threadIdx.x;      // 0 .. B*H*W-1 (exact)
    int pos = tid % (H * W);
    int b   = tid / (H * W);
    const float* xb = x + (size_t)b * C * H * W + pos;
    float acc[CM];
#pragma unroll
    for (int co = 0; co < CM; ++co) acc[co] = 0.f;
    for (int ci = 0; ci < C; ++ci) {
        float xv = xb[ci * (H * W)];
#pragma unroll
        for (int co = 0; co < CM; ++co)
            acc[co] = fmaf(xv, wc[co * C + ci], acc[co]);   // wc idx wave-uniform -> s_load
    }
    float* cb = comp + (size_t)b * CM * H * W + pos;
#pragma unroll
    for (int co = 0; co < CM; ++co) cb[co * (H * W)] = acc[co];
}

__global__ __launch_bounds__(256) void encoder_k(const float* __restrict__ comp,
                                                 const float* __restrict__ we,
                                                 float* __restrict__ ker) {
    int tid = blockIdx.x * 256 + threadIdx.x;      // 0 .. B*HD*WD-1 (exact)
    int wd = tid % WD;
    int t  = tid / WD;
    int hd = t % HD;
    int b  = t / HD;
    const float* cb = comp + (size_t)b * CM * H * W;
    float acc[KC];
#pragma unroll
    for (int ko = 0; ko < KC; ++ko) acc[ko] = 0.f;
    for (int ci = 0; ci < CM; ++ci) {
#pragma unroll
        for (int kh = 0; kh < 3; ++kh) {
            int r    = 2 * hd + kh - 1;
            bool rok = (unsigned)r < H;
            int rc   = min(max(r, 0), H - 1);
#pragma unroll
            for (int kw = 0; kw < 3; ++kw) {
                int c0   = 2 * wd + kw - 1;
                bool ok  = rok && ((unsigned)c0 < W);
                int cc   = min(max(c0, 0), W - 1);
                float cv = cb[ci * (H * W) + rc * W + cc];
                cv = ok ? cv : 0.f;
#pragma unroll
                for (int ko = 0; ko < KC; ++ko)
                    acc[ko] = fmaf(cv, we[((ko * CM + ci) * 3 + kh) * 3 + kw], acc[ko]);
            }
        }
    }
    // softmax over the 25 kernel taps
    float m = acc[0];
#pragma unroll
    for (int ko = 1; ko < KC; ++ko) m = fmaxf(m, acc[ko]);
    float s = 0.f;
#pragma unroll
    for (int ko = 0; ko < KC; ++ko) { acc[ko] = __expf(acc[ko] - m); s += acc[ko]; }
    float inv = 1.f / s;
    float* kb = ker + (size_t)b * KC * HD * WD + hd * WD + wd;
#pragma unroll
    for (int ko = 0; ko < KC; ++ko) kb[ko * (HD * WD)] = acc[ko] * inv;
}

__global__ __launch_bounds__(256) void reassemble_k(const float* __restrict__ x,
                                                    const float* __restrict__ ker,
                                                    float* __restrict__ out) {
    int tid = blockIdx.x * 256 + threadIdx.x;      // 0 .. B*C*HD*WD-1 (exact)
    int wd = tid % WD;
    int t  = tid / WD;
    int hd = t % HD;
    int t2 = t / HD;
    int c  = t2 % C;
    int b  = t2 / C;
    const float* xb = x + ((size_t)b * C + c) * (H * W);
    const float* kb = ker + (size_t)b * KC * HD * WD + hd * WD + wd;
    float sum = 0.f;
#pragma unroll
    for (int i = 0; i < 5; ++i) {
        int r    = 2 * hd + i - 2;
        bool rok = (unsigned)r < H;
        int rc   = min(max(r, 0), H - 1);
#pragma unroll
        for (int j = 0; j < 5; ++j) {
            int c0  = 2 * wd + j - 2;
            bool ok = rok && ((unsigned)c0 < W);
            int cc  = min(max(c0, 0), W - 1);
            float xv = xb[rc * W + cc];
            float kv = kb[(i * 5 + j) * (HD * WD)];
            sum += ok ? xv * kv : 0.f;
        }
    }
    out[tid] = sum;
}

extern "C" void kernel_launch(void* const* d_in, const int* in_sizes, int n_in,
                              void* d_out, int out_size, void* d_ws, size_t ws_size,
                              hipStream_t stream) {
    const float* x  = (const float*)d_in[0];
    const float* wc = (const float*)d_in[1];
    const float* we = (const float*)d_in[2];
    float* out  = (float*)d_out;
    float* comp = (float*)d_ws;                       // B*CM*H*W  = 3,276,800 f32
    float* ker  = comp + (size_t)B * CM * H * W;      // B*KC*HD*WD = 1,280,000 f32

    compress_k  <<<(B * H * W) / 256,      256, 0, stream>>>(x, wc, comp);
    encoder_k   <<<(B * HD * WD) / 256,    256, 0, stream>>>(comp, we, ker);
    reassemble_k<<<(B * C * HD * WD) / 256, 256, 0, stream>>>(x, ker, out);
}

// Round 2
// 118.720 us; speedup vs baseline: 1.4363x; 1.4363x over previous
//
#include <hip/hip_runtime.h>

// CARAFE++ downsample: B=8, C=128, H=W=160, stride 2 -> HD=WD=80
#define B   8
#define C   128
#define H   160
#define W   160
#define HW  (H*W)       // 25600
#define CM  16
#define KC  25
#define HD  80
#define WD  80
#define HWD (HD*WD)     // 6400
#define CH  8           // channels per reassemble thread

// ---- stage 1: 1x1 conv 128->16, 2 pixels/thread (float2, HBM-bound) ----
__global__ __launch_bounds__(256) void compress_k(const float* __restrict__ x,
                                                  const float* __restrict__ wc,
                                                  float* __restrict__ comp) {
    int gid = blockIdx.x * 256 + threadIdx.x;       // 0 .. B*HW/2-1
    int b   = gid / (HW / 2);
    int pos = (gid % (HW / 2)) * 2;
    const float* xb = x + (size_t)b * C * HW + pos;
    float2 acc[CM];
#pragma unroll
    for (int co = 0; co < CM; ++co) acc[co] = make_float2(0.f, 0.f);
    for (int ci = 0; ci < C; ++ci) {
        float2 v = *reinterpret_cast<const float2*>(xb + (size_t)ci * HW);
#pragma unroll
        for (int co = 0; co < CM; ++co) {
            float wv = wc[co * C + ci];             // uniform -> s_load
            acc[co].x = fmaf(v.x, wv, acc[co].x);
            acc[co].y = fmaf(v.y, wv, acc[co].y);
        }
    }
    float* cb = comp + (size_t)b * CM * HW + pos;
#pragma unroll
    for (int co = 0; co < CM; ++co)
        *reinterpret_cast<float2*>(cb + co * HW) = acc[co];
}

// ---- stage 2: 3x3 s2 conv 16->25 + softmax; ci split across 4 waves ----
__global__ __launch_bounds__(256) void encoder_k(const float* __restrict__ comp,
                                                 const float* __restrict__ we,
                                                 float* __restrict__ ker) {
    __shared__ float part[4][KC][64];
    int lane = threadIdx.x & 63;
    int sub  = __builtin_amdgcn_readfirstlane(threadIdx.x >> 6);  // wave id, uniform
    int p  = blockIdx.x * 64 + lane;                // pixel 0..51199
    int b  = p / HWD;
    int r2 = p % HWD;
    int hd = r2 / WD;
    int wd = r2 % WD;
    const float* cb = comp + (size_t)b * CM * HW;
    float acc[KC];
#pragma unroll
    for (int ko = 0; ko < KC; ++ko) acc[ko] = 0.f;
#pragma unroll
    for (int cii = 0; cii < 4; ++cii) {
        int ci = sub * 4 + cii;                     // uniform -> we stays s_load
#pragma unroll
        for (int kh = 0; kh < 3; ++kh) {
            int r    = 2 * hd + kh - 1;
            bool rok = (unsigned)r < H;
            int rc   = min(max(r, 0), H - 1);
#pragma unroll
            for (int kw = 0; kw < 3; ++kw) {
                int c0  = 2 * wd + kw - 1;
                bool ok = rok && ((unsigned)c0 < W);
                int cc  = min(max(c0, 0), W - 1);
                float cv = cb[(size_t)ci * HW + rc * W + cc];
                cv = ok ? cv : 0.f;
#pragma unroll
                for (int ko = 0; ko < KC; ++ko)
                    acc[ko] = fmaf(cv, we[((ko * CM + ci) * 3 + kh) * 3 + kw], acc[ko]);
            }
        }
    }
#pragma unroll
    for (int ko = 0; ko < KC; ++ko) part[sub][ko][lane] = acc[ko];
    __syncthreads();
    if (threadIdx.x < 64) {
        float a[KC];
#pragma unroll
        for (int ko = 0; ko < KC; ++ko)
            a[ko] = (part[0][ko][lane] + part[1][ko][lane]) +
                    (part[2][ko][lane] + part[3][ko][lane]);
        float m = a[0];
#pragma unroll
        for (int ko = 1; ko < KC; ++ko) m = fmaxf(m, a[ko]);
        float s = 0.f;
#pragma unroll
        for (int ko = 0; ko < KC; ++ko) { a[ko] = __expf(a[ko] - m); s += a[ko]; }
        float inv = 1.f / s;
        float* kp = ker + (size_t)b * KC * HWD + hd * WD + wd;
#pragma unroll
        for (int ko = 0; ko < KC; ++ko) kp[ko * HWD] = a[ko] * inv;
    }
}

// ---- stage 3: 5x5 s2 reassembly; wd-pair x 8 channels per thread ----
// Window cols [4pr-2 .. 4pr+4] per row = float2 + float4 + float, all aligned.
// Boundaries via zero-masked kernel weights; clamped offsets stay in-bounds.
__global__ __launch_bounds__(128) void reassemble_k(const float* __restrict__ x,
                                                    const float* __restrict__ ker,
                                                    float* __restrict__ out) {
    int bcg  = blockIdx.x / 25;                     // 0..127
    int pblk = blockIdx.x % 25;
    int b   = bcg >> 4;
    int cg  = bcg & 15;
    int pix = pblk * 128 + threadIdx.x;             // 0..3199
    int hd  = pix / 40;
    int pr  = pix % 40;
    int wd0 = pr * 2;                               // output cols (wd0, wd0+1)

    // load 2x25 kernel weights (float2: dense coalesced) and zero-mask OOB taps
    const float* kb = ker + (size_t)b * KC * HWD + hd * WD + wd0;
    float k0m[KC], k1m[KC];
    bool rv[5];
#pragma unroll
    for (int i = 0; i < 5; ++i) rv[i] = (unsigned)(2 * hd + i - 2) < H;
    bool c0lo = (pr > 0);                           // out0 taps j=0,1 valid?
    bool c1hi = (pr < 39);                          // out1 tap  j=4  valid?
#pragma unroll
    for (int i = 0; i < 5; ++i)
#pragma unroll
        for (int j = 0; j < 5; ++j) {
            float2 kv = *reinterpret_cast<const float2*>(kb + (i * 5 + j) * HWD);
            k0m[i * 5 + j] = (rv[i] && (j >= 2 || c0lo)) ? kv.x : 0.f;
            k1m[i * 5 + j] = (rv[i] && (j <= 3 || c1hi)) ? kv.y : 0.f;
        }

    // per-row window offsets (elements), clamped so every address is in-bounds;
    // any clamp-shifted value only feeds a zero-masked tap.
    int offA[5], offB[5], offC[5];
#pragma unroll
    for (int i = 0; i < 5; ++i) {
        int rc = min(max(2 * hd + i - 2, 0), H - 1);
        int ro = rc * W + 4 * pr;
        offA[i] = max(ro - 2, 0);                   // cols 4pr-2,4pr-1 (8B aligned)
        offB[i] = ro;                               // cols 4pr..4pr+3 (16B aligned)
        offC[i] = min(ro + 4, HW - 1);              // col  4pr+4
    }

    const float* xc = x + (size_t)(b * C + cg * CH) * HW;   // block-uniform base
    float* ob = out + ((size_t)(b * C + cg * CH) * HD + hd) * WD + wd0;
    for (int c8 = 0; c8 < CH; ++c8) {
        float acc0 = 0.f, acc1 = 0.f;
#pragma unroll
        for (int i = 0; i < 5; ++i) {
            float2 a  = *reinterpret_cast<const float2*>(xc + offA[i]);
            float4 bq = *reinterpret_cast<const float4*>(xc + offB[i]);
            float  cs = xc[offC[i]];
            // window w[0..6] = a.x a.y bq.x bq.y bq.z bq.w cs  (cols 4pr-2..4pr+4)
            acc0 = fmaf(a.x,  k0m[i * 5 + 0], acc0);
            acc0 = fmaf(a.y,  k0m[i * 5 + 1], acc0);
            acc0 = fmaf(bq.x, k0m[i * 5 + 2], acc0);
            acc0 = fmaf(bq.y, k0m[i * 5 + 3], acc0);
            acc0 = fmaf(bq.z, k0m[i * 5 + 4], acc0);
            acc1 = fmaf(bq.x, k1m[i * 5 + 0], acc1);
            acc1 = fmaf(bq.y, k1m[i * 5 + 1], acc1);
            acc1 = fmaf(bq.z, k1m[i * 5 + 2], acc1);
            acc1 = fmaf(bq.w, k1m[i * 5 + 3], acc1);
            acc1 = fmaf(cs,   k1m[i * 5 + 4], acc1);
        }
        *reinterpret_cast<float2*>(ob) = make_float2(acc0, acc1);
        xc += HW;
        ob += HWD;
    }
}

extern "C" void kernel_launch(void* const* d_in, const int* in_sizes, int n_in,
                              void* d_out, int out_size, void* d_ws, size_t ws_size,
                              hipStream_t stream) {
    const float* x  = (const float*)d_in[0];
    const float* wc = (const float*)d_in[1];
    const float* we = (const float*)d_in[2];
    float* out  = (float*)d_out;
    float* comp = (float*)d_ws;                       // B*CM*HW   = 3,276,800 f32
    float* ker  = comp + (size_t)B * CM * HW;         // B*KC*HWD  = 1,280,000 f32

    compress_k  <<<(B * HW / 2) / 256, 256, 0, stream>>>(x, wc, comp);   // 400 blocks
    encoder_k   <<<(B * HWD) / 64,     256, 0, stream>>>(comp, we, ker); // 800 blocks
    reassemble_k<<<B * 16 * 25,        128, 0, stream>>>(x, ker, out);   // 3200 blocks
}

// Round 3
// 97.594 us; speedup vs baseline: 1.7472x; 1.2165x over previous
//
#include <hip/hip_runtime.h>

// CARAFE++ downsample: B=8, C=128, H=W=160, stride 2 -> HD=WD=80
#define B   8
#define C   128
#define H   160
#define W   160
#define HW  (H*W)       // 25600
#define CM  16
#define KC  25
#define HD  80
#define WD  80
#define HWD (HD*WD)     // 6400
#define CH  4           // channels per reassemble thread

// ---- stage 1: 1x1 conv 128->16, 2 pixels/thread, ci unrolled x16 ----
__global__ __launch_bounds__(256) void compress_k(const float* __restrict__ x,
                                                  const float* __restrict__ wc,
                                                  float* __restrict__ comp) {
    int gid = blockIdx.x * 256 + threadIdx.x;       // 0 .. B*HW/2-1
    int b   = gid / (HW / 2);
    int pos = (gid % (HW / 2)) * 2;
    const float* xb = x + (size_t)b * C * HW + pos;
    float2 acc[CM];
#pragma unroll
    for (int co = 0; co < CM; ++co) acc[co] = make_float2(0.f, 0.f);
    for (int ci0 = 0; ci0 < C; ci0 += 16) {
        float2 v[16];
#pragma unroll
        for (int u = 0; u < 16; ++u)                // 16 loads in flight
            v[u] = *reinterpret_cast<const float2*>(xb + (size_t)(ci0 + u) * HW);
#pragma unroll
        for (int u = 0; u < 16; ++u)
#pragma unroll
            for (int co = 0; co < CM; ++co) {
                float wv = wc[co * C + ci0 + u];    // uniform -> s_load
                acc[co].x = fmaf(v[u].x, wv, acc[co].x);
                acc[co].y = fmaf(v[u].y, wv, acc[co].y);
            }
    }
    float* cb = comp + (size_t)b * CM * HW + pos;
#pragma unroll
    for (int co = 0; co < CM; ++co)
        *reinterpret_cast<float2*>(cb + co * HW) = acc[co];
}

// ---- stage 2: 3x3 s2 conv 16->25 + softmax; ci split across 4 waves ----
__global__ __launch_bounds__(256) void encoder_k(const float* __restrict__ comp,
                                                 const float* __restrict__ we,
                                                 float* __restrict__ ker) {
    __shared__ float part[4][KC][64];
    int lane = threadIdx.x & 63;
    int sub  = __builtin_amdgcn_readfirstlane(threadIdx.x >> 6);  // wave id, uniform
    int p  = blockIdx.x * 64 + lane;                // pixel 0..51199
    int b  = p / HWD;
    int r2 = p % HWD;
    int hd = r2 / WD;
    int wd = r2 % WD;
    const float* cb = comp + (size_t)b * CM * HW;
    float acc[KC];
#pragma unroll
    for (int ko = 0; ko < KC; ++ko) acc[ko] = 0.f;
#pragma unroll
    for (int cii = 0; cii < 4; ++cii) {
        int ci = sub * 4 + cii;                     // uniform -> we stays s_load
#pragma unroll
        for (int kh = 0; kh < 3; ++kh) {
            int r    = 2 * hd + kh - 1;
            bool rok = (unsigned)r < H;
            int rc   = min(max(r, 0), H - 1);
#pragma unroll
            for (int kw = 0; kw < 3; ++kw) {
                int c0  = 2 * wd + kw - 1;
                bool ok = rok && ((unsigned)c0 < W);
                int cc  = min(max(c0, 0), W - 1);
                float cv = cb[(size_t)ci * HW + rc * W + cc];
                cv = ok ? cv : 0.f;
#pragma unroll
                for (int ko = 0; ko < KC; ++ko)
                    acc[ko] = fmaf(cv, we[((ko * CM + ci) * 3 + kh) * 3 + kw], acc[ko]);
            }
        }
    }
#pragma unroll
    for (int ko = 0; ko < KC; ++ko) part[sub][ko][lane] = acc[ko];
    __syncthreads();
    if (threadIdx.x < 64) {
        float a[KC];
#pragma unroll
        for (int ko = 0; ko < KC; ++ko)
            a[ko] = (part[0][ko][lane] + part[1][ko][lane]) +
                    (part[2][ko][lane] + part[3][ko][lane]);
        float m = a[0];
#pragma unroll
        for (int ko = 1; ko < KC; ++ko) m = fmaxf(m, a[ko]);
        float s = 0.f;
#pragma unroll
        for (int ko = 0; ko < KC; ++ko) { a[ko] = __expf(a[ko] - m); s += a[ko]; }
        float inv = 1.f / s;
        float* kp = ker + (size_t)b * KC * HWD + hd * WD + wd;
#pragma unroll
        for (int ko = 0; ko < KC; ++ko) kp[ko * HWD] = a[ko] * inv;
    }
}

// ---- stage 3: 5x5 s2 reassembly; wd-pair x 4 channels per thread ----
// Window cols [4pr-2 .. 4pr+4] per row = float2 + float4 + float, all aligned.
// Boundaries via zero-masked kernel weights; clamped offsets stay in-bounds.
__global__ __launch_bounds__(128, 4) void reassemble_k(const float* __restrict__ x,
                                                       const float* __restrict__ ker,
                                                       float* __restrict__ out) {
    int bcg  = blockIdx.x / 25;                     // 0..255 = (b, cg)
    int pblk = blockIdx.x % 25;
    int b   = bcg >> 5;
    int cg  = bcg & 31;
    int pix = pblk * 128 + threadIdx.x;             // 0..3199
    int hd  = pix / 40;
    int pr  = pix % 40;
    int wd0 = pr * 2;                               // output cols (wd0, wd0+1)

    // load 2x25 kernel weights (float2: dense coalesced) and zero-mask OOB taps
    const float* kb = ker + (size_t)b * KC * HWD + hd * WD + wd0;
    float k0m[KC], k1m[KC];
    bool rv[5];
#pragma unroll
    for (int i = 0; i < 5; ++i) rv[i] = (unsigned)(2 * hd + i - 2) < H;
    bool c0lo = (pr > 0);                           // out0 taps j=0,1 valid?
    bool c1hi = (pr < 39);                          // out1 tap  j=4  valid?
#pragma unroll
    for (int i = 0; i < 5; ++i)
#pragma unroll
        for (int j = 0; j < 5; ++j) {
            float2 kv = *reinterpret_cast<const float2*>(kb + (i * 5 + j) * HWD);
            k0m[i * 5 + j] = (rv[i] && (j >= 2 || c0lo)) ? kv.x : 0.f;
            k1m[i * 5 + j] = (rv[i] && (j <= 3 || c1hi)) ? kv.y : 0.f;
        }

    // per-row window offsets (elements), clamped so every address is in-bounds;
    // any clamp-shifted value only feeds a zero-masked tap.
    int offA[5], offB[5], offC[5];
#pragma unroll
    for (int i = 0; i < 5; ++i) {
        int rc = min(max(2 * hd + i - 2, 0), H - 1);
        int ro = rc * W + 4 * pr;
        offA[i] = max(ro - 2, 0);                   // cols 4pr-2,4pr-1 (8B aligned)
        offB[i] = ro;                               // cols 4pr..4pr+3 (16B aligned)
        offC[i] = min(ro + 4, HW - 1);              // col  4pr+4
    }

    const float* xc = x + (size_t)(b * C + cg * CH) * HW;   // block-uniform base
    float* ob = out + ((size_t)(b * C + cg * CH) * HD + hd) * WD + wd0;
#pragma unroll
    for (int c8 = 0; c8 < CH; ++c8) {
        float acc0 = 0.f, acc1 = 0.f;
#pragma unroll
        for (int i = 0; i < 5; ++i) {
            float2 a  = *reinterpret_cast<const float2*>(xc + offA[i]);
            float4 bq = *reinterpret_cast<const float4*>(xc + offB[i]);
            float  cs = xc[offC[i]];
            // window w[0..6] = a.x a.y bq.x bq.y bq.z bq.w cs  (cols 4pr-2..4pr+4)
            acc0 = fmaf(a.x,  k0m[i * 5 + 0], acc0);
            acc0 = fmaf(a.y,  k0m[i * 5 + 1], acc0);
            acc0 = fmaf(bq.x, k0m[i * 5 + 2], acc0);
            acc0 = fmaf(bq.y, k0m[i * 5 + 3], acc0);
            acc0 = fmaf(bq.z, k0m[i * 5 + 4], acc0);
            acc1 = fmaf(bq.x, k1m[i * 5 + 0], acc1);
            acc1 = fmaf(bq.y, k1m[i * 5 + 1], acc1);
            acc1 = fmaf(bq.z, k1m[i * 5 + 2], acc1);
            acc1 = fmaf(bq.w, k1m[i * 5 + 3], acc1);
            acc1 = fmaf(cs,   k1m[i * 5 + 4], acc1);
        }
        *reinterpret_cast<float2*>(ob) = make_float2(acc0, acc1);
        xc += HW;
        ob += HWD;
    }
}

extern "C" void kernel_launch(void* const* d_in, const int* in_sizes, int n_in,
                              void* d_out, int out_size, void* d_ws, size_t ws_size,
                              hipStream_t stream) {
    const float* x  = (const float*)d_in[0];
    const float* wc = (const float*)d_in[1];
    const float* we = (const float*)d_in[2];
    float* out  = (float*)d_out;
    float* comp = (float*)d_ws;                       // B*CM*HW   = 3,276,800 f32
    float* ker  = comp + (size_t)B * CM * HW;         // B*KC*HWD  = 1,280,000 f32

    compress_k  <<<(B * HW / 2) / 256, 256, 0, stream>>>(x, wc, comp);   // 400 blocks
    encoder_k   <<<(B * HWD) / 64,     256, 0, stream>>>(comp, we, ker); // 800 blocks
    reassemble_k<<<B * 32 * 25,        128, 0, stream>>>(x, ker, out);   // 6400 blocks
}

// Round 4
// 96.282 us; speedup vs baseline: 1.7711x; 1.0136x over previous
//
#include <hip/hip_runtime.h>

// CARAFE++ downsample: B=8, C=128, H=W=160, stride 2 -> HD=WD=80
#define B   8
#define C   128
#define H   160
#define W   160
#define HW  (H*W)       // 25600
#define CM  16
#define KC  25
#define HD  80
#define WD  80
#define HWD (HD*WD)     // 6400
#define CH  2           // channels per reassemble thread

// ---- stage 1: 1x1 conv 128->16, 2 pixels/thread, ci unrolled x16 ----
__global__ __launch_bounds__(256) void compress_k(const float* __restrict__ x,
                                                  const float* __restrict__ wc,
                                                  float* __restrict__ comp) {
    int gid = blockIdx.x * 256 + threadIdx.x;       // 0 .. B*HW/2-1
    int b   = gid / (HW / 2);
    int pos = (gid % (HW / 2)) * 2;
    const float* xb = x + (size_t)b * C * HW + pos;
    float2 acc[CM];
#pragma unroll
    for (int co = 0; co < CM; ++co) acc[co] = make_float2(0.f, 0.f);
    for (int ci0 = 0; ci0 < C; ci0 += 16) {
        float2 v[16];
#pragma unroll
        for (int u = 0; u < 16; ++u)                // 16 loads in flight
            v[u] = *reinterpret_cast<const float2*>(xb + (size_t)(ci0 + u) * HW);
#pragma unroll
        for (int u = 0; u < 16; ++u)
#pragma unroll
            for (int co = 0; co < CM; ++co) {
                float wv = wc[co * C + ci0 + u];    // uniform -> s_load
                acc[co].x = fmaf(v[u].x, wv, acc[co].x);
                acc[co].y = fmaf(v[u].y, wv, acc[co].y);
            }
    }
    float* cb = comp + (size_t)b * CM * HW + pos;
#pragma unroll
    for (int co = 0; co < CM; ++co)
        *reinterpret_cast<float2*>(cb + co * HW) = acc[co];
}

// ---- stage 2: 3x3 s2 conv 16->25 + softmax; ci split across 4 waves ----
__global__ __launch_bounds__(256) void encoder_k(const float* __restrict__ comp,
                                                 const float* __restrict__ we,
                                                 float* __restrict__ ker) {
    __shared__ float part[4][KC][64];
    int lane = threadIdx.x & 63;
    int sub  = __builtin_amdgcn_readfirstlane(threadIdx.x >> 6);  // wave id, uniform
    int p  = blockIdx.x * 64 + lane;                // pixel 0..51199
    int b  = p / HWD;
    int r2 = p % HWD;
    int hd = r2 / WD;
    int wd = r2 % WD;
    const float* cb = comp + (size_t)b * CM * HW;
    float acc[KC];
#pragma unroll
    for (int ko = 0; ko < KC; ++ko) acc[ko] = 0.f;
#pragma unroll
    for (int cii = 0; cii < 4; ++cii) {
        int ci = sub * 4 + cii;                     // uniform -> we stays s_load
#pragma unroll
        for (int kh = 0; kh < 3; ++kh) {
            int r    = 2 * hd + kh - 1;
            bool rok = (unsigned)r < H;
            int rc   = min(max(r, 0), H - 1);
#pragma unroll
            for (int kw = 0; kw < 3; ++kw) {
                int c0  = 2 * wd + kw - 1;
                bool ok = rok && ((unsigned)c0 < W);
                int cc  = min(max(c0, 0), W - 1);
                float cv = cb[(size_t)ci * HW + rc * W + cc];
                cv = ok ? cv : 0.f;
#pragma unroll
                for (int ko = 0; ko < KC; ++ko)
                    acc[ko] = fmaf(cv, we[((ko * CM + ci) * 3 + kh) * 3 + kw], acc[ko]);
            }
        }
    }
#pragma unroll
    for (int ko = 0; ko < KC; ++ko) part[sub][ko][lane] = acc[ko];
    __syncthreads();
    if (threadIdx.x < 64) {
        float a[KC];
#pragma unroll
        for (int ko = 0; ko < KC; ++ko)
            a[ko] = (part[0][ko][lane] + part[1][ko][lane]) +
                    (part[2][ko][lane] + part[3][ko][lane]);
        float m = a[0];
#pragma unroll
        for (int ko = 1; ko < KC; ++ko) m = fmaxf(m, a[ko]);
        float s = 0.f;
#pragma unroll
        for (int ko = 0; ko < KC; ++ko) { a[ko] = __expf(a[ko] - m); s += a[ko]; }
        float inv = 1.f / s;
        float* kp = ker + (size_t)b * KC * HWD + hd * WD + wd;
#pragma unroll
        for (int ko = 0; ko < KC; ++ko) kp[ko * HWD] = a[ko] * inv;
    }
}

// ---- stage 3: 5x5 s2 reassembly; wd-pair x 2 channels per thread ----
// 25600 waves (latency hiding), XCD-aware block mapping so the 64 channel-
// group blocks of one (b,pixel-block) run adjacently on ONE XCD: ker tile
// (~0.64 MB) and x window (~0.9 MB) stay L2-resident across channel groups.
__global__ __launch_bounds__(128) void reassemble_k(const float* __restrict__ x,
                                                    const float* __restrict__ ker,
                                                    float* __restrict__ out) {
    // bid = (s*64 + cgrp)*8 + r, where v = b*25 + pblk, r = v%8, s = v/8
    int bid  = blockIdx.x;
    int r_   = bid & 7;
    int t_   = bid >> 3;
    int cgrp = t_ & 63;                             // 0..63 (2 channels each)
    int s_   = t_ >> 6;                             // 0..24
    int v_   = s_ * 8 + r_;                         // 0..199
    int b    = v_ / 25;
    int pblk = v_ % 25;

    int pix = pblk * 128 + threadIdx.x;             // 0..3199
    int hd  = pix / 40;
    int pr  = pix % 40;
    int wd0 = pr * 2;                               // output cols (wd0, wd0+1)

    // load 2x25 kernel weights (float2: dense coalesced) and zero-mask OOB taps
    const float* kb = ker + (size_t)b * KC * HWD + hd * WD + wd0;
    float k0m[KC], k1m[KC];
    bool rv[5];
#pragma unroll
    for (int i = 0; i < 5; ++i) rv[i] = (unsigned)(2 * hd + i - 2) < H;
    bool c0lo = (pr > 0);                           // out0 taps j=0,1 valid?
    bool c1hi = (pr < 39);                          // out1 tap  j=4  valid?
#pragma unroll
    for (int i = 0; i < 5; ++i)
#pragma unroll
        for (int j = 0; j < 5; ++j) {
            float2 kv = *reinterpret_cast<const float2*>(kb + (i * 5 + j) * HWD);
            k0m[i * 5 + j] = (rv[i] && (j >= 2 || c0lo)) ? kv.x : 0.f;
            k1m[i * 5 + j] = (rv[i] && (j <= 3 || c1hi)) ? kv.y : 0.f;
        }

    // per-row window offsets (elements), clamped so every address is in-bounds;
    // any clamp-shifted value only feeds a zero-masked tap.
    int offA[5], offB[5], offC[5];
#pragma unroll
    for (int i = 0; i < 5; ++i) {
        int rc = min(max(2 * hd + i - 2, 0), H - 1);
        int ro = rc * W + 4 * pr;
        offA[i] = max(ro - 2, 0);                   // cols 4pr-2,4pr-1 (8B aligned)
        offB[i] = ro;                               // cols 4pr..4pr+3 (16B aligned)
        offC[i] = min(ro + 4, HW - 1);              // col  4pr+4
    }

    const float* xc = x + (size_t)(b * C + cgrp * CH) * HW;   // block-uniform base
    float* ob = out + ((size_t)(b * C + cgrp * CH) * HD + hd) * WD + wd0;
#pragma unroll
    for (int c8 = 0; c8 < CH; ++c8) {
        float acc0 = 0.f, acc1 = 0.f;
#pragma unroll
        for (int i = 0; i < 5; ++i) {
            float2 a  = *reinterpret_cast<const float2*>(xc + offA[i]);
            float4 bq = *reinterpret_cast<const float4*>(xc + offB[i]);
            float  cs = xc[offC[i]];
            // window w[0..6] = a.x a.y bq.x bq.y bq.z bq.w cs  (cols 4pr-2..4pr+4)
            acc0 = fmaf(a.x,  k0m[i * 5 + 0], acc0);
            acc0 = fmaf(a.y,  k0m[i * 5 + 1], acc0);
            acc0 = fmaf(bq.x, k0m[i * 5 + 2], acc0);
            acc0 = fmaf(bq.y, k0m[i * 5 + 3], acc0);
            acc0 = fmaf(bq.z, k0m[i * 5 + 4], acc0);
            acc1 = fmaf(bq.x, k1m[i * 5 + 0], acc1);
            acc1 = fmaf(bq.y, k1m[i * 5 + 1], acc1);
            acc1 = fmaf(bq.z, k1m[i * 5 + 2], acc1);
            acc1 = fmaf(bq.w, k1m[i * 5 + 3], acc1);
            acc1 = fmaf(cs,   k1m[i * 5 + 4], acc1);
        }
        *reinterpret_cast<float2*>(ob) = make_float2(acc0, acc1);
        xc += HW;
        ob += HWD;
    }
}

extern "C" void kernel_launch(void* const* d_in, const int* in_sizes, int n_in,
                              void* d_out, int out_size, void* d_ws, size_t ws_size,
                              hipStream_t stream) {
    const float* x  = (const float*)d_in[0];
    const float* wc = (const float*)d_in[1];
    const float* we = (const float*)d_in[2];
    float* out  = (float*)d_out;
    float* comp = (float*)d_ws;                       // B*CM*HW   = 3,276,800 f32
    float* ker  = comp + (size_t)B * CM * HW;         // B*KC*HWD  = 1,280,000 f32

    compress_k  <<<(B * HW / 2) / 256, 256, 0, stream>>>(x, wc, comp);   // 400 blocks
    encoder_k   <<<(B * HWD) / 64,     256, 0, stream>>>(comp, we, ker); // 800 blocks
    reassemble_k<<<B * 64 * 25,        128, 0, stream>>>(x, ker, out);   // 12800 blocks
}